// Round 10
// baseline (623.416 us; speedup 1.0000x reference)
//
#include <hip/hip_runtime.h>
#include <hip/hip_bf16.h>
#include <hip/hip_cooperative_groups.h>

namespace cg = cooperative_groups;

// SelfAttention: B=4, S=2048, E=1024, fp32 in/out, bf16 internal compute.
// Y[b,j,d] = sum_i softmax_i(Q_j.K_i / sqrt(S)) * V[i,d]
//
// R10: back to the R7 dataflow (best: 231.8us), fused into ONE cooperative
// persistent kernel (1024 blocks, 4/CU) with grid.sync() between phases:
//   P0 cvt fp32->bf16 (X, Wq, Wk, Wv) + zero l
//   P1 QKV GEMM (1536 tiles; Q,K bf16 -> d_out; V -> Vt transposed)
//   P2 scores: P = exp(QK^T * scale) bf16 + row-sum atomics into l
//   P3 Y = (P @ Vt^T) / l -> fp32 out
// Removes 3 dispatch boundaries (~5us each measured R4->R5). Fallback to the
// 4-dispatch R7 path if cooperative launch is rejected.
// K-loop: BK=64, XOR-swizzled LDS via global_load_lds w=16, 0 bank conflicts.

typedef __bf16 bf16x8 __attribute__((ext_vector_type(8)));
typedef float  f32x4  __attribute__((ext_vector_type(4)));

__device__ __forceinline__ unsigned short f2bf(float f) {
    unsigned int u = __float_as_uint(f);
    u = (u + 0x7FFFu + ((u >> 16) & 1u)) >> 16;   // round-to-nearest-even
    return (unsigned short)u;
}

// ---- shared K-loop (R3 structure) ----
#define GEMM_DECLS                                                      \
    const int t    = threadIdx.x;                                       \
    const int wave = t >> 6;                                            \
    const int lane = t & 63;                                            \
    const int quad = lane >> 4;                                         \
    const int lr   = lane & 15;                                         \
    const int wm   = (wave >> 1) * 64;                                  \
    const int wn   = (wave & 1) * 64;                                   \
    const int sx   = lr & 7;                                            \
    const int lrow = lane >> 3;                                         \
    const int gch  = ((lane & 7) ^ (lrow & 7)) * 8;

#define GEMM_KLOOP(Aptr, Bptr, LDA, LDB)                                \
    for (int k0 = 0; k0 < K; k0 += 64) {                                \
        _Pragma("unroll")                                               \
        for (int r = 0; r < 4; ++r) {                                   \
            const int rowb = wave * 8 + r * 32;                         \
            const int row  = rowb + lrow;                               \
            const long goffA = (long)(m0 + row) * (LDA) + k0 + gch;     \
            const long goffB = (long)(n0 + row) * (LDB) + k0 + gch;     \
            __builtin_amdgcn_global_load_lds(                           \
                (const __attribute__((address_space(1))) void*)((Aptr) + goffA), \
                (__attribute__((address_space(3))) void*)(&lsA[rowb * 64]), 16, 0, 0); \
            __builtin_amdgcn_global_load_lds(                           \
                (const __attribute__((address_space(1))) void*)((Bptr) + goffB), \
                (__attribute__((address_space(3))) void*)(&lsB[rowb * 64]), 16, 0, 0); \
        }                                                               \
        __syncthreads();                                                \
        _Pragma("unroll")                                               \
        for (int h = 0; h < 2; ++h) {                                   \
            const int cp = ((h * 4 + quad) ^ sx) * 8;                   \
            bf16x8 af[4], bfr[4];                                       \
            _Pragma("unroll")                                           \
            for (int i = 0; i < 4; ++i) {                               \
                af[i]  = __builtin_bit_cast(bf16x8,                     \
                          *reinterpret_cast<const uint4*>(&lsA[(wm + i * 16 + lr) * 64 + cp])); \
                bfr[i] = __builtin_bit_cast(bf16x8,                     \
                          *reinterpret_cast<const uint4*>(&lsB[(wn + i * 16 + lr) * 64 + cp])); \
            }                                                           \
            _Pragma("unroll")                                           \
            for (int i = 0; i < 4; ++i)                                 \
                _Pragma("unroll")                                       \
                for (int j = 0; j < 4; ++j)                             \
                    acc[i][j] = __builtin_amdgcn_mfma_f32_16x16x32_bf16(af[i], bfr[j], acc[i][j], 0, 0, 0); \
        }                                                               \
        __syncthreads();                                                \
    }

// ---- phase bodies (shared by mega-kernel and fallback kernels) ----

__device__ __forceinline__ void cvt_step(
    long i, const float* __restrict__ X, const float* __restrict__ Wq,
    const float* __restrict__ Wk, const float* __restrict__ Wv,
    unsigned short* __restrict__ Xb, unsigned short* __restrict__ Wqb,
    unsigned short* __restrict__ Wkb, unsigned short* __restrict__ Wvb,
    float* __restrict__ l)
{
    if (i < 8192) l[i] = 0.0f;
    const float* src; unsigned short* dst; long off;
    if (i < 2097152L) { src = X; dst = Xb; off = i; }
    else {
        long j = i - 2097152L;
        int w = (int)(j >> 18);          // 262144 float4 per 1024^2 matrix
        off = j & 262143L;
        src = (w == 0) ? Wq : (w == 1) ? Wk : Wv;
        dst = (w == 0) ? Wqb : (w == 1) ? Wkb : Wvb;
    }
    float4 v = reinterpret_cast<const float4*>(src)[off];
    ushort4 o;
    o.x = f2bf(v.x); o.y = f2bf(v.y); o.z = f2bf(v.z); o.w = f2bf(v.w);
    reinterpret_cast<ushort4*>(dst)[off] = o;
}

__device__ __forceinline__ void qkv_tile(
    int tt, unsigned short* lsA, unsigned short* lsB,
    const unsigned short* __restrict__ Xb,
    const unsigned short* __restrict__ Wqb, const unsigned short* __restrict__ Wkb,
    const unsigned short* __restrict__ Wvb,
    const float* __restrict__ bq, const float* __restrict__ bk,
    const float* __restrict__ bv_,
    unsigned short* __restrict__ Qb, unsigned short* __restrict__ Kb,
    unsigned short* __restrict__ Vt)
{
    const int g   = tt & 7;
    const int jj  = tt >> 3;
    const int xx  = jj & 7;
    const int yin = (jj >> 3) & 7;
    const int z   = jj >> 6;

    const unsigned short* B = (z == 0) ? Wqb : (z == 1) ? Wkb : Wvb;
    const float* bias       = (z == 0) ? bq  : (z == 1) ? bk  : bv_;

    const int n0 = xx * 128;
    const int m0 = (g * 8 + yin) * 128;
    const int K = 1024;

    GEMM_DECLS
    f32x4 acc[4][4] = {};
    GEMM_KLOOP(Xb, B, 1024, 1024)

#pragma unroll
    for (int j = 0; j < 4; ++j) {
        const int n = n0 + wn + j * 16 + lr;
        const float bvv = bias[n];
#pragma unroll
        for (int i = 0; i < 4; ++i) {
            const int mbase = m0 + wm + i * 16 + quad * 4;
            if (z < 2) {
                unsigned short* C = (z == 0) ? Qb : Kb;
#pragma unroll
                for (int r = 0; r < 4; ++r)
                    C[(long)(mbase + r) * 1024 + n] = f2bf(acc[i][j][r] + bvv);
            } else {
                ushort4 o;
                o.x = f2bf(acc[i][j][0] + bvv);
                o.y = f2bf(acc[i][j][1] + bvv);
                o.z = f2bf(acc[i][j][2] + bvv);
                o.w = f2bf(acc[i][j][3] + bvv);
                long boff = (long)(mbase >> 11) * (1024L * 2048) + (long)n * 2048 + (mbase & 2047);
                *reinterpret_cast<ushort4*>(Vt + boff) = o;
            }
        }
    }
}

__device__ __forceinline__ void scores_tile(
    int id, unsigned short* lsA, unsigned short* lsB,
    const unsigned short* __restrict__ Q, const unsigned short* __restrict__ Kp,
    unsigned short* __restrict__ P, float* __restrict__ l)
{
    const float scale = 0.022097086912079608f;
    const int g   = id & 7;
    const int uu  = id >> 3;
    const int bz  = g >> 1;
    const int mh  = g & 1;
    const int yin = uu & 7;
    const int xx  = uu >> 3;                 // 0..15

    const unsigned short* A = Q  + (long)bz * 2048 * 1024;
    const unsigned short* B = Kp + (long)bz * 2048 * 1024;
    unsigned short* Pb = P + (long)bz * 2048 * 2048;
    float* lb = l + bz * 2048;

    const int n0 = xx * 128;
    const int m0 = (mh * 8 + yin) * 128;
    const int K = 1024;

    GEMM_DECLS
    f32x4 acc[4][4] = {};
    GEMM_KLOOP(A, B, 1024, 1024)

#pragma unroll
    for (int i = 0; i < 4; ++i) {
#pragma unroll
        for (int r = 0; r < 4; ++r) {
            const int m = m0 + wm + i * 16 + quad * 4 + r;
            float psum = 0.0f;
#pragma unroll
            for (int j = 0; j < 4; ++j) {
                const float p = __expf(acc[i][j][r] * scale);
                psum += p;
                const int n = n0 + wn + j * 16 + lr;
                Pb[(long)m * 2048 + n] = f2bf(p);
            }
#pragma unroll
            for (int o = 1; o < 16; o <<= 1) psum += __shfl_xor(psum, o, 64);
            if (lr == 0) atomicAdd(&lb[m], psum);
        }
    }
}

__device__ __forceinline__ void y_tile(
    int id, unsigned short* lsA, unsigned short* lsB,
    const unsigned short* __restrict__ P, const unsigned short* __restrict__ Vt,
    const float* __restrict__ l, float* __restrict__ out)
{
    const int g   = id & 7;
    const int uu  = id >> 3;
    const int bz  = g >> 1;
    const int mh  = g & 1;
    const int yin = uu & 7;
    const int xx  = uu >> 3;                 // 0..7

    const unsigned short* A = P  + (long)bz * 2048 * 2048;
    const unsigned short* B = Vt + (long)bz * 1024 * 2048;
    const float* lb = l + bz * 2048;
    float* C = out + (long)bz * 2048 * 1024;

    const int n0 = xx * 128;
    const int m0 = (mh * 8 + yin) * 128;
    const int K = 2048;

    GEMM_DECLS
    f32x4 acc[4][4] = {};
    GEMM_KLOOP(A, B, 2048, 2048)

    float linv[4][4];
#pragma unroll
    for (int i = 0; i < 4; ++i)
#pragma unroll
        for (int r = 0; r < 4; ++r)
            linv[i][r] = 1.0f / lb[m0 + wm + i * 16 + quad * 4 + r];

#pragma unroll
    for (int j = 0; j < 4; ++j) {
        const int n = n0 + wn + j * 16 + lr;
#pragma unroll
        for (int i = 0; i < 4; ++i) {
            const int mbase = m0 + wm + i * 16 + quad * 4;
#pragma unroll
            for (int r = 0; r < 4; ++r)
                C[(long)(mbase + r) * 1024 + n] = acc[i][j][r] * linv[i][r];
        }
    }
}

// ---- mega-kernel: all phases, grid.sync() between ----
__global__ __launch_bounds__(256, 4)
void fused_attn(const float* __restrict__ X,  const float* __restrict__ Wq,
                const float* __restrict__ Wk, const float* __restrict__ Wv,
                const float* __restrict__ bq, const float* __restrict__ bk,
                const float* __restrict__ bv_,
                unsigned short* __restrict__ Xb,
                unsigned short* __restrict__ Wqb, unsigned short* __restrict__ Wkb,
                unsigned short* __restrict__ Wvb,
                unsigned short* __restrict__ Qb, unsigned short* __restrict__ Kb,
                unsigned short* __restrict__ Vt, unsigned short* __restrict__ P,
                float* __restrict__ l, float* __restrict__ out)
{
    __shared__ unsigned short lsA[128 * 64];
    __shared__ unsigned short lsB[128 * 64];
    cg::grid_group grid = cg::this_grid();
    const int bid = blockIdx.x;

    // P0: cvt (11264 virtual blocks over 1024)
    for (int vb = bid; vb < 11264; vb += 1024)
        cvt_step((long)vb * 256 + threadIdx.x, X, Wq, Wk, Wv, Xb, Wqb, Wkb, Wvb, l);
    grid.sync();

    // P1: QKV (1536 tiles; per-CU load exactly 6 tiles -- balanced)
    for (int tt = bid; tt < 1536; tt += 1024)
        qkv_tile(tt, lsA, lsB, Xb, Wqb, Wkb, Wvb, bq, bk, bv_, Qb, Kb, Vt);
    grid.sync();

    // P2: scores (1024 tiles)
    scores_tile(bid, lsA, lsB, Qb, Kb, P, l);
    grid.sync();

    // P3: Y (512 tiles; blocks c and c+256 per CU busy -- balanced)
    if (bid < 512)
        y_tile(bid, lsA, lsB, P, Vt, l, out);
}

// ---- fallback standalone kernels (exact R7 path) ----
__global__ __launch_bounds__(256)
void cvt_all(const float* __restrict__ X,  const float* __restrict__ Wq,
             const float* __restrict__ Wk, const float* __restrict__ Wv,
             unsigned short* __restrict__ Xb,  unsigned short* __restrict__ Wqb,
             unsigned short* __restrict__ Wkb, unsigned short* __restrict__ Wvb,
             float* __restrict__ l) {
    cvt_step((long)blockIdx.x * 256 + threadIdx.x, X, Wq, Wk, Wv, Xb, Wqb, Wkb, Wvb, l);
}

__global__ __launch_bounds__(256, 4)
void gemm_qkv(const unsigned short* __restrict__ Xb,
              const unsigned short* __restrict__ Wqb,
              const unsigned short* __restrict__ Wkb,
              const unsigned short* __restrict__ Wvb,
              const float* __restrict__ bq, const float* __restrict__ bk,
              const float* __restrict__ bv_,
              unsigned short* __restrict__ Qb, unsigned short* __restrict__ Kb,
              unsigned short* __restrict__ Vt) {
    __shared__ unsigned short lsA[128 * 64];
    __shared__ unsigned short lsB[128 * 64];
    qkv_tile(blockIdx.x, lsA, lsB, Xb, Wqb, Wkb, Wvb, bq, bk, bv_, Qb, Kb, Vt);
}

__global__ __launch_bounds__(256, 4)
void gemm_scores(const unsigned short* __restrict__ Q,
                 const unsigned short* __restrict__ Kp,
                 unsigned short* __restrict__ P, float* __restrict__ l) {
    __shared__ unsigned short lsA[128 * 64];
    __shared__ unsigned short lsB[128 * 64];
    scores_tile(blockIdx.x, lsA, lsB, Q, Kp, P, l);
}

__global__ __launch_bounds__(256, 4)
void gemm_y(const unsigned short* __restrict__ P,
            const unsigned short* __restrict__ Vt,
            const float* __restrict__ l, float* __restrict__ out) {
    __shared__ unsigned short lsA[128 * 64];
    __shared__ unsigned short lsB[128 * 64];
    y_tile(blockIdx.x, lsA, lsB, P, Vt, l, out);
}

extern "C" void kernel_launch(void* const* d_in, const int* in_sizes, int n_in,
                              void* d_out, int out_size, void* d_ws, size_t ws_size,
                              hipStream_t stream) {
    const float* X  = (const float*)d_in[0];
    const float* Wk = (const float*)d_in[1];
    const float* bk = (const float*)d_in[2];
    const float* Wq = (const float*)d_in[3];
    const float* bq = (const float*)d_in[4];
    const float* Wv = (const float*)d_in[5];
    const float* bv = (const float*)d_in[6];
    float* out = (float*)d_out;

    const size_t MB = 1024 * 1024;
    if (ws_size < 80 * MB) return;   // visible failure instead of OOB corruption

    char* ws = (char*)d_ws;
    unsigned short* Vt  = (unsigned short*)(ws);            // 16 MiB
    unsigned short* P   = (unsigned short*)(ws + 16 * MB);  // 32 MiB
    unsigned short* Xbf = (unsigned short*)(ws + 16 * MB);  // overlaps P: Xbf dead before P written
    float*          l   = (float*)(ws + 48 * MB);           // 32 KiB
    unsigned short* Wqb = (unsigned short*)(ws + 49 * MB);  // 2 MiB
    unsigned short* Wkb = (unsigned short*)(ws + 51 * MB);  // 2 MiB
    unsigned short* Wvb = (unsigned short*)(ws + 53 * MB);  // 2 MiB
    // Q,K bf16 live in d_out (32 MiB) until P3 overwrites it
    unsigned short* Qb = (unsigned short*)d_out;
    unsigned short* Kb = Qb + 8192L * 1024;

    void* args[] = { (void*)&X, (void*)&Wq, (void*)&Wk, (void*)&Wv,
                     (void*)&bq, (void*)&bk, (void*)&bv,
                     (void*)&Xbf, (void*)&Wqb, (void*)&Wkb, (void*)&Wvb,
                     (void*)&Qb, (void*)&Kb, (void*)&Vt, (void*)&P,
                     (void*)&l, (void*)&out };

    hipError_t e = hipLaunchCooperativeKernel((const void*)fused_attn,
                                              dim3(1024), dim3(256),
                                              args, 0u, stream);
    if (e != hipSuccess) {
        // fallback: exact R7 4-dispatch path
        dim3 blk(256);
        cvt_all<<<11264, blk, 0, stream>>>(X, Wq, Wk, Wv, Xbf, Wqb, Wkb, Wvb, l);
        gemm_qkv<<<1536, blk, 0, stream>>>(Xbf, Wqb, Wkb, Wvb, bq, bk, bv, Qb, Kb, Vt);
        gemm_scores<<<1024, blk, 0, stream>>>(Qb, Kb, P, l);
        gemm_y<<<512, blk, 0, stream>>>(P, Vt, l, out);
    }
}

// Round 11
// 231.667 us; speedup vs baseline: 2.6910x; 2.6910x over previous
//
#include <hip/hip_runtime.h>
#include <hip/hip_bf16.h>

// SelfAttention: B=4, S=2048, E=1024, fp32 in/out, bf16 internal compute.
// Y[b,j,d] = sum_i softmax_i(Q_j.K_i / sqrt(S)) * V[i,d]
//
// R11: exact restore of R6 (best measured: 230.3us). 4 dispatches:
//   cvt_all -> gemm_qkv (XCD-banded) -> gemm_scores (fused exp + row-sum
//   atomics, XCD-banded) -> gemm_y (scale by 1/l, XCD-banded).
// K-loop: BK=64, XOR-swizzled LDS via global_load_lds w=16, 0 bank conflicts.
// R7-R10 experiments (launch_bounds 4, yin-fastest, algebraic K-elimination,
// cooperative mega-kernel) were all neutral-to-regressive; this config is the
// measured optimum of the m97-class structure on this problem.

typedef __bf16 bf16x8 __attribute__((ext_vector_type(8)));
typedef float  f32x4  __attribute__((ext_vector_type(4)));

__device__ __forceinline__ unsigned short f2bf(float f) {
    unsigned int u = __float_as_uint(f);
    u = (u + 0x7FFFu + ((u >> 16) & 1u)) >> 16;   // round-to-nearest-even
    return (unsigned short)u;
}

// Converts X + Wq/Wk/Wv fp32->bf16, and zeroes the softmax-denominator array.
__global__ __launch_bounds__(256)
void cvt_all(const float* __restrict__ X,  const float* __restrict__ Wq,
             const float* __restrict__ Wk, const float* __restrict__ Wv,
             unsigned short* __restrict__ Xb,  unsigned short* __restrict__ Wqb,
             unsigned short* __restrict__ Wkb, unsigned short* __restrict__ Wvb,
             float* __restrict__ l) {
    long i = (long)blockIdx.x * 256 + threadIdx.x;   // float4 index
    if (i < 8192) l[i] = 0.0f;                       // 4*2048 row sums
    const float* src; unsigned short* dst; long off;
    if (i < 2097152L) { src = X; dst = Xb; off = i; }
    else {
        long j = i - 2097152L;
        int w = (int)(j >> 18);          // 262144 float4 per 1024^2 matrix
        off = j & 262143L;
        src = (w == 0) ? Wq : (w == 1) ? Wk : Wv;
        dst = (w == 0) ? Wqb : (w == 1) ? Wkb : Wvb;
    }
    float4 v = reinterpret_cast<const float4*>(src)[off];
    ushort4 o;
    o.x = f2bf(v.x); o.y = f2bf(v.y); o.z = f2bf(v.z); o.w = f2bf(v.w);
    reinterpret_cast<ushort4*>(dst)[off] = o;
}

// ---- shared K-loop (R3 structure) ----
#define GEMM_DECLS                                                      \
    const int t    = threadIdx.x;                                       \
    const int wave = t >> 6;                                            \
    const int lane = t & 63;                                            \
    const int quad = lane >> 4;                                         \
    const int lr   = lane & 15;                                         \
    const int wm   = (wave >> 1) * 64;                                  \
    const int wn   = (wave & 1) * 64;                                   \
    const int sx   = lr & 7;                                            \
    const int lrow = lane >> 3;                                         \
    const int gch  = ((lane & 7) ^ (lrow & 7)) * 8;

#define GEMM_KLOOP(Aptr, Bptr, LDA, LDB)                                \
    for (int k0 = 0; k0 < K; k0 += 64) {                                \
        _Pragma("unroll")                                               \
        for (int r = 0; r < 4; ++r) {                                   \
            const int rowb = wave * 8 + r * 32;                         \
            const int row  = rowb + lrow;                               \
            const long goffA = (long)(m0 + row) * (LDA) + k0 + gch;     \
            const long goffB = (long)(n0 + row) * (LDB) + k0 + gch;     \
            __builtin_amdgcn_global_load_lds(                           \
                (const __attribute__((address_space(1))) void*)((Aptr) + goffA), \
                (__attribute__((address_space(3))) void*)(&lsA[rowb * 64]), 16, 0, 0); \
            __builtin_amdgcn_global_load_lds(                           \
                (const __attribute__((address_space(1))) void*)((Bptr) + goffB), \
                (__attribute__((address_space(3))) void*)(&lsB[rowb * 64]), 16, 0, 0); \
        }                                                               \
        __syncthreads();                                                \
        _Pragma("unroll")                                               \
        for (int h = 0; h < 2; ++h) {                                   \
            const int cp = ((h * 4 + quad) ^ sx) * 8;                   \
            bf16x8 af[4], bfr[4];                                       \
            _Pragma("unroll")                                           \
            for (int i = 0; i < 4; ++i) {                               \
                af[i]  = __builtin_bit_cast(bf16x8,                     \
                          *reinterpret_cast<const uint4*>(&lsA[(wm + i * 16 + lr) * 64 + cp])); \
                bfr[i] = __builtin_bit_cast(bf16x8,                     \
                          *reinterpret_cast<const uint4*>(&lsB[(wn + i * 16 + lr) * 64 + cp])); \
            }                                                           \
            _Pragma("unroll")                                           \
            for (int i = 0; i < 4; ++i)                                 \
                _Pragma("unroll")                                       \
                for (int j = 0; j < 4; ++j)                             \
                    acc[i][j] = __builtin_amdgcn_mfma_f32_16x16x32_bf16(af[i], bfr[j], acc[i][j], 0, 0, 0); \
        }                                                               \
        __syncthreads();                                                \
    }

// Fused QKV projection, XCD-band swizzled 1D grid of 1536 blocks:
// id = g + 8*(x + 8*y_in + 64*z); XCD g owns m-band y = g*8+y_in.
// z=0 -> Q (bf16), z=1 -> K (bf16), z=2 -> V transposed Vt[b][n][s].
__global__ __launch_bounds__(256, 2)
void gemm_qkv(const unsigned short* __restrict__ Xb,
              const unsigned short* __restrict__ Wqb,
              const unsigned short* __restrict__ Wkb,
              const unsigned short* __restrict__ Wvb,
              const float* __restrict__ bq, const float* __restrict__ bk,
              const float* __restrict__ bv_,
              unsigned short* __restrict__ Qb, unsigned short* __restrict__ Kb,
              unsigned short* __restrict__ Vt)
{
    __shared__ unsigned short lsA[128 * 64];
    __shared__ unsigned short lsB[128 * 64];

    const int id  = blockIdx.x;
    const int g   = id & 7;
    const int jj  = id >> 3;
    const int xx  = jj & 7;
    const int yin = (jj >> 3) & 7;
    const int z   = jj >> 6;

    const unsigned short* A = Xb;
    const unsigned short* B = (z == 0) ? Wqb : (z == 1) ? Wkb : Wvb;
    const float* bias       = (z == 0) ? bq  : (z == 1) ? bk  : bv_;

    const int n0 = xx * 128;
    const int m0 = (g * 8 + yin) * 128;
    const int K = 1024;

    GEMM_DECLS
    f32x4 acc[4][4] = {};
    GEMM_KLOOP(A, B, 1024, 1024)

#pragma unroll
    for (int j = 0; j < 4; ++j) {
        const int n = n0 + wn + j * 16 + lr;
        const float bvv = bias[n];
#pragma unroll
        for (int i = 0; i < 4; ++i) {
            const int mbase = m0 + wm + i * 16 + quad * 4;
            if (z < 2) {
                unsigned short* C = (z == 0) ? Qb : Kb;
#pragma unroll
                for (int r = 0; r < 4; ++r)
                    C[(long)(mbase + r) * 1024 + n] = f2bf(acc[i][j][r] + bvv);
            } else {
                ushort4 o;
                o.x = f2bf(acc[i][j][0] + bvv);
                o.y = f2bf(acc[i][j][1] + bvv);
                o.z = f2bf(acc[i][j][2] + bvv);
                o.w = f2bf(acc[i][j][3] + bvv);
                long boff = (long)(mbase >> 11) * (1024L * 2048) + (long)n * 2048 + (mbase & 2047);
                *reinterpret_cast<ushort4*>(Vt + boff) = o;
            }
        }
    }
}

// Scores + fused exp: P[b][j][i] = exp(Q_j.K_i * scale) (bf16),
// l[b*2048+j] += row sums (atomic). 1D grid 1024, XCD-banded:
// g = id&7 -> batch g>>1, m-half g&1; u = id>>3 -> x = u&15, yin = u>>4.
__global__ __launch_bounds__(256, 2)
void gemm_scores(const unsigned short* __restrict__ Q,
                 const unsigned short* __restrict__ Kp,
                 unsigned short* __restrict__ P, float* __restrict__ l,
                 float scale)
{
    __shared__ unsigned short lsA[128 * 64];
    __shared__ unsigned short lsB[128 * 64];

    const int id  = blockIdx.x;
    const int g   = id & 7;
    const int u   = id >> 3;
    const int bz  = g >> 1;
    const int mh  = g & 1;
    const int xx  = u & 15;
    const int yin = u >> 4;                 // 0..7

    const unsigned short* A = Q  + (long)bz * 2048 * 1024;
    const unsigned short* B = Kp + (long)bz * 2048 * 1024;
    unsigned short* Pb = P + (long)bz * 2048 * 2048;
    float* lb = l + bz * 2048;

    const int n0 = xx * 128;
    const int m0 = (mh * 8 + yin) * 128;
    const int K = 1024;

    GEMM_DECLS
    f32x4 acc[4][4] = {};
    GEMM_KLOOP(A, B, 1024, 1024)

#pragma unroll
    for (int i = 0; i < 4; ++i) {
#pragma unroll
        for (int r = 0; r < 4; ++r) {
            const int m = m0 + wm + i * 16 + quad * 4 + r;
            float psum = 0.0f;
#pragma unroll
            for (int j = 0; j < 4; ++j) {
                const float p = __expf(acc[i][j][r] * scale);
                psum += p;
                const int n = n0 + wn + j * 16 + lr;
                Pb[(long)m * 2048 + n] = f2bf(p);
            }
#pragma unroll
            for (int o = 1; o < 16; o <<= 1) psum += __shfl_xor(psum, o, 64);
            if (lr == 0) atomicAdd(&lb[m], psum);
        }
    }
}

// Y[b][j][d] = (1/l[b,j]) * sum_i P[b][j][i]*Vt[b][d][i] -> fp32 out.
// 1D grid 512, XCD-banded: g = id&7 -> batch g>>1, m-half g&1;
// u = id>>3 -> x = u&7, yin = u>>3. 64 blocks/XCD = fully resident.
__global__ __launch_bounds__(256, 2)
void gemm_y(const unsigned short* __restrict__ P,
            const unsigned short* __restrict__ Vt,
            const float* __restrict__ l, float* __restrict__ out)
{
    __shared__ unsigned short lsA[128 * 64];
    __shared__ unsigned short lsB[128 * 64];

    const int id  = blockIdx.x;
    const int g   = id & 7;
    const int u   = id >> 3;
    const int bz  = g >> 1;
    const int mh  = g & 1;
    const int xx  = u & 7;
    const int yin = u >> 3;                 // 0..7

    const unsigned short* A = P  + (long)bz * 2048 * 2048;
    const unsigned short* B = Vt + (long)bz * 1024 * 2048;
    const float* lb = l + bz * 2048;
    float* C = out + (long)bz * 2048 * 1024;

    const int n0 = xx * 128;
    const int m0 = (mh * 8 + yin) * 128;
    const int K = 2048;

    GEMM_DECLS
    f32x4 acc[4][4] = {};
    GEMM_KLOOP(A, B, 2048, 2048)

    float linv[4][4];
#pragma unroll
    for (int i = 0; i < 4; ++i)
#pragma unroll
        for (int r = 0; r < 4; ++r)
            linv[i][r] = 1.0f / lb[m0 + wm + i * 16 + quad * 4 + r];

#pragma unroll
    for (int j = 0; j < 4; ++j) {
        const int n = n0 + wn + j * 16 + lr;
#pragma unroll
        for (int i = 0; i < 4; ++i) {
            const int mbase = m0 + wm + i * 16 + quad * 4;
#pragma unroll
            for (int r = 0; r < 4; ++r)
                C[(long)(mbase + r) * 1024 + n] = acc[i][j][r] * linv[i][r];
        }
    }
}

extern "C" void kernel_launch(void* const* d_in, const int* in_sizes, int n_in,
                              void* d_out, int out_size, void* d_ws, size_t ws_size,
                              hipStream_t stream) {
    const float* X  = (const float*)d_in[0];
    const float* Wk = (const float*)d_in[1];
    const float* bk = (const float*)d_in[2];
    const float* Wq = (const float*)d_in[3];
    const float* bq = (const float*)d_in[4];
    const float* Wv = (const float*)d_in[5];
    const float* bv = (const float*)d_in[6];
    float* out = (float*)d_out;

    const size_t MB = 1024 * 1024;
    if (ws_size < 80 * MB) return;   // visible failure instead of OOB corruption

    char* ws = (char*)d_ws;
    unsigned short* Vt  = (unsigned short*)(ws);            // 16 MiB
    unsigned short* P   = (unsigned short*)(ws + 16 * MB);  // 32 MiB
    unsigned short* Xbf = (unsigned short*)(ws + 16 * MB);  // overlaps P: dead before P written
    float*          l   = (float*)(ws + 48 * MB);           // 32 KiB
    unsigned short* Wqb = (unsigned short*)(ws + 49 * MB);
    unsigned short* Wkb = (unsigned short*)(ws + 51 * MB);
    unsigned short* Wvb = (unsigned short*)(ws + 53 * MB);
    // Q,K bf16 live in d_out (32 MiB) until gemm_y overwrites it
    unsigned short* Qb = (unsigned short*)d_out;
    unsigned short* Kb = Qb + 8192L * 1024;

    dim3 blk(256);

    // 1) fp32->bf16 conversions + zero l (2883584 float4 units)
    cvt_all<<<2883584 / 256, blk, 0, stream>>>(X, Wq, Wk, Wv, Xbf, Wqb, Wkb, Wvb, l);

    // 2) fused QKV projections, XCD-band swizzled 1D grid
    gemm_qkv<<<1536, blk, 0, stream>>>(Xbf, Wqb, Wkb, Wvb, bq, bk, bv, Qb, Kb, Vt);

    // 3) scores + exp + row-sum atomics, XCD-banded 1D grid
    gemm_scores<<<1024, blk, 0, stream>>>(Qb, Kb, P, l, 0.022097086912079608f);

    // 4) Y = (P @ Vt^T) / l, XCD-banded 1D grid
    gemm_y<<<512, blk, 0, stream>>>(P, Vt, l, out);
}